// Round 1
// baseline (346.657 us; speedup 1.0000x reference)
//
#include <hip/hip_runtime.h>
#include <math.h>

#define K_CAT 1024
#define DIM   64
#define B_    16
#define HW    4096        // 64*64
#define NPIX  65536       // B_*HW
#define TOTAL 4194304     // NPIX*DIM
#define KSPLIT 4
#define KPW   (K_CAT / KSPLIT)   // 256 k's per wave

// ---------------- norms: nrm[k] = sum_c emb[k][c]^2 ----------------
__global__ void vq_norms(const float* __restrict__ emb, float* __restrict__ nrm) {
    int k = blockIdx.x * blockDim.x + threadIdx.x;
    if (k < K_CAT) {
        const float4* e4 = reinterpret_cast<const float4*>(emb + (size_t)k * DIM);
        float s = 0.f;
        #pragma unroll
        for (int i = 0; i < DIM / 4; ++i) {
            float4 v = e4[i];
            s += v.x * v.x + v.y * v.y + v.z * v.z + v.w * v.w;
        }
        nrm[k] = s;
    }
}

// f64 exact re-score of one candidate: ||e_k||^2 - 2*ze.e_k  (in double)
__device__ inline double rescore_f64(const float* __restrict__ emb,
                                     const float ze[DIM], int k) {
    const float* e = emb + (size_t)k * DIM;
    double nrm = 0.0, dot = 0.0;
    #pragma unroll
    for (int c = 0; c < DIM; ++c) {
        double ev = (double)e[c];
        nrm = fma(ev, ev, nrm);
        dot = fma((double)ze[c], ev, dot);
    }
    return nrm - 2.0 * dot;
}

// ---------------- main: argmin + gather + per-block loss ----------------
__global__ __launch_bounds__(256) void vq_main(
    const float* __restrict__ x, const float* __restrict__ emb,
    const float* __restrict__ nrm, float* __restrict__ out,
    float* __restrict__ partials)
{
    __shared__ float s_b1s[KSPLIT][64];
    __shared__ int   s_b1k[KSPLIT][64];
    __shared__ float s_b2s[KSPLIT][64];
    __shared__ int   s_b2k[KSPLIT][64];

    const int lane = threadIdx.x & 63;
    // force wave-uniform so emb/nrm loads scalarize to s_load
    const int wave = __builtin_amdgcn_readfirstlane(threadIdx.x >> 6);
    const int pixbase = blockIdx.x * 64;
    const int b  = pixbase / HW;              // uniform per block
    const int hw = (pixbase % HW) + lane;     // consecutive w across lanes

    const float* xp = x + (size_t)b * DIM * HW + hw;
    float ze[DIM];
    #pragma unroll
    for (int c = 0; c < DIM; ++c) ze[c] = xp[(size_t)c * HW];

    const int kbase = wave * KPW;
    float b1s = 1e30f; int b1k = kbase;
    float b2s = 1e30f; int b2k = kbase;

    for (int kk = 0; kk < KPW; kk += 4) {
        const int k = kbase + kk;
        const float* e0 = emb + (size_t)(k + 0) * DIM;
        const float* e1 = emb + (size_t)(k + 1) * DIM;
        const float* e2 = emb + (size_t)(k + 2) * DIM;
        const float* e3 = emb + (size_t)(k + 3) * DIM;
        float d0a = 0.f, d0b = 0.f, d1a = 0.f, d1b = 0.f;
        float d2a = 0.f, d2b = 0.f, d3a = 0.f, d3b = 0.f;
        #pragma unroll
        for (int c = 0; c < DIM; c += 2) {
            float za = ze[c], zb = ze[c + 1];
            d0a = fmaf(za, e0[c], d0a); d0b = fmaf(zb, e0[c + 1], d0b);
            d1a = fmaf(za, e1[c], d1a); d1b = fmaf(zb, e1[c + 1], d1b);
            d2a = fmaf(za, e2[c], d2a); d2b = fmaf(zb, e2[c + 1], d2b);
            d3a = fmaf(za, e3[c], d3a); d3b = fmaf(zb, e3[c + 1], d3b);
        }
        float s0 = fmaf(-2.f, d0a + d0b, nrm[k + 0]);
        float s1 = fmaf(-2.f, d1a + d1b, nrm[k + 1]);
        float s2 = fmaf(-2.f, d2a + d2b, nrm[k + 2]);
        float s3 = fmaf(-2.f, d3a + d3b, nrm[k + 3]);
        // ascending-k scan, strict < keeps first occurrence of the min
        if (s0 < b1s) { b2s = b1s; b2k = b1k; b1s = s0; b1k = k + 0; }
        else if (s0 < b2s) { b2s = s0; b2k = k + 0; }
        if (s1 < b1s) { b2s = b1s; b2k = b1k; b1s = s1; b1k = k + 1; }
        else if (s1 < b2s) { b2s = s1; b2k = k + 1; }
        if (s2 < b1s) { b2s = b1s; b2k = b1k; b1s = s2; b1k = k + 2; }
        else if (s2 < b2s) { b2s = s2; b2k = k + 2; }
        if (s3 < b1s) { b2s = b1s; b2k = b1k; b1s = s3; b1k = k + 3; }
        else if (s3 < b2s) { b2s = s3; b2k = k + 3; }
    }

    s_b1s[wave][lane] = b1s; s_b1k[wave][lane] = b1k;
    s_b2s[wave][lane] = b2s; s_b2k[wave][lane] = b2k;
    __syncthreads();

    if (wave != 0) return;   // wave 0 does epilogue (64 px * 64 c)

    // merge 8 candidates (per-wave best+second), waves ascending => k ascending
    float g1s = 1e30f; int g1k = 0; float g2s = 1e30f; int g2k = 0;
    #pragma unroll
    for (int w2 = 0; w2 < KSPLIT; ++w2) {
        float cs = s_b1s[w2][lane]; int ck = s_b1k[w2][lane];
        if (cs < g1s) { g2s = g1s; g2k = g1k; g1s = cs; g1k = ck; }
        else if (cs < g2s) { g2s = cs; g2k = ck; }
        cs = s_b2s[w2][lane]; ck = s_b2k[w2][lane];
        if (cs < g1s) { g2s = g1s; g2k = g1k; g1s = cs; g1k = ck; }
        else if (cs < g2s) { g2s = cs; g2k = ck; }
    }

    int fk = g1k;
    // near-tie: resolve exactly in f64 (rare; covers fp32 rounding ~1e-7)
    if (g2s - g1s < 1e-6f) {
        double sA = rescore_f64(emb, ze, g1k);
        double sB = rescore_f64(emb, ze, g2k);
        if (sB < sA || (sB == sA && g2k < g1k)) fk = g2k;
    }

    // gather + straight-through output + loss partial
    const float4* e4 = reinterpret_cast<const float4*>(emb + (size_t)fk * DIM);
    float* op = out + (size_t)b * DIM * HW + hw;
    float lsum = 0.f;
    #pragma unroll
    for (int cq = 0; cq < DIM / 4; ++cq) {
        float4 ev = e4[cq];
        float z0 = ze[4 * cq + 0], z1 = ze[4 * cq + 1];
        float z2 = ze[4 * cq + 2], z3 = ze[4 * cq + 3];
        op[(size_t)(4 * cq + 0) * HW] = (ev.x - z0) + z0;
        op[(size_t)(4 * cq + 1) * HW] = (ev.y - z1) + z1;
        op[(size_t)(4 * cq + 2) * HW] = (ev.z - z2) + z2;
        op[(size_t)(4 * cq + 3) * HW] = (ev.w - z3) + z3;
        float d0 = z0 - ev.x, d1 = z1 - ev.y, d2 = z2 - ev.z, d3 = z3 - ev.w;
        lsum = fmaf(d0, d0, lsum); lsum = fmaf(d1, d1, lsum);
        lsum = fmaf(d2, d2, lsum); lsum = fmaf(d3, d3, lsum);
    }
    #pragma unroll
    for (int off = 32; off > 0; off >>= 1) lsum += __shfl_down(lsum, off, 64);
    if (lane == 0) partials[blockIdx.x] = lsum;
}

// ---------------- final deterministic loss reduce ----------------
__global__ void vq_loss_final(const float* __restrict__ partials,
                              float* __restrict__ loss_out) {
    __shared__ float sm[4];
    const int tid = threadIdx.x;
    const int lane = tid & 63, wave = tid >> 6;
    float s = 0.f;
    #pragma unroll
    for (int i = 0; i < 4; ++i) s += partials[tid + i * 256];
    #pragma unroll
    for (int off = 32; off > 0; off >>= 1) s += __shfl_down(s, off, 64);
    if (lane == 0) sm[wave] = s;
    __syncthreads();
    if (tid == 0) {
        float t = sm[0] + sm[1] + sm[2] + sm[3];
        loss_out[0] = 1.25f * t / (float)TOTAL;
    }
}

extern "C" void kernel_launch(void* const* d_in, const int* in_sizes, int n_in,
                              void* d_out, int out_size, void* d_ws, size_t ws_size,
                              hipStream_t stream) {
    const float* x   = (const float*)d_in[0];
    const float* emb = (const float*)d_in[1];
    float* out = (float*)d_out;
    float* nrm = (float*)d_ws;            // [0, 1024)
    float* partials = nrm + K_CAT;        // [1024, 2048)

    vq_norms<<<K_CAT / 256, 256, 0, stream>>>(emb, nrm);
    vq_main<<<NPIX / 64, 256, 0, stream>>>(x, emb, nrm, out, partials);
    vq_loss_final<<<1, 256, 0, stream>>>(partials, out + TOTAL);
}

// Round 2
// 77.008 us; speedup vs baseline: 4.5016x; 4.5016x over previous
//
#include <hip/hip_runtime.h>

#define K_CAT 1024
#define DIM   64
#define HW    4096              // 64*64
#define NPIX  65536             // 16*4096
#define TOTAL 4194304           // NPIX*DIM

typedef __attribute__((ext_vector_type(8))) short  bfrag8;   // 8 bf16 (4 VGPRs)
typedef __attribute__((ext_vector_type(4))) float  f32x4;

__device__ inline unsigned short f32_to_bf16(float f) {
    unsigned int u = __float_as_uint(f);
    unsigned int r = (u + 0x7fffu + ((u >> 16) & 1u)) >> 16;   // RNE
    return (unsigned short)r;
}

// ---------- prep: emb -> bf16 table (row-major [K][64]) + f32 norms ----------
__global__ void vq_prep(const float* __restrict__ emb,
                        unsigned short* __restrict__ embb,
                        float* __restrict__ nrm) {
    int k = blockIdx.x * blockDim.x + threadIdx.x;
    if (k >= K_CAT) return;
    const float4* e4 = reinterpret_cast<const float4*>(emb + (size_t)k * DIM);
    unsigned int pk[32];
    float s = 0.f;
    #pragma unroll
    for (int i = 0; i < 16; ++i) {
        float4 v = e4[i];
        s += v.x * v.x + v.y * v.y + v.z * v.z + v.w * v.w;
        pk[2 * i]     = (unsigned)f32_to_bf16(v.x) | ((unsigned)f32_to_bf16(v.y) << 16);
        pk[2 * i + 1] = (unsigned)f32_to_bf16(v.z) | ((unsigned)f32_to_bf16(v.w) << 16);
    }
    nrm[k] = s;
    uint4* dst = reinterpret_cast<uint4*>(embb + (size_t)k * DIM);
    #pragma unroll
    for (int i = 0; i < 8; ++i)
        dst[i] = make_uint4(pk[4 * i], pk[4 * i + 1], pk[4 * i + 2], pk[4 * i + 3]);
}

// ---------- main: MFMA scoring + argmin + gather + loss partials ----------
__global__ __launch_bounds__(256) void vq_argmin(
    const float* __restrict__ x, const unsigned short* __restrict__ embb,
    const float* __restrict__ nrm, const float* __restrict__ embf,
    float* __restrict__ out, float* __restrict__ partials)
{
    __shared__ int   s_idx[64];
    __shared__ float s_part[4];

    const int tid  = threadIdx.x;
    const int lane = tid & 63;
    const int wave = __builtin_amdgcn_readfirstlane(tid >> 6);
    const int c15  = lane & 15;        // A: pixel row / B: code col / D: code col
    const int kg   = lane >> 4;        // k-group 0..3

    const int pixbase = blockIdx.x * 64;
    const int b   = pixbase / HW;      // uniform per block
    const int hw0 = pixbase % HW;      // uniform per block
    const int whw = hw0 + wave * 16;   // this wave's 16-pixel tile

    // ---- load ze A-fragments (pixel = c15, chans 8*kg+j / 32+8*kg+j) ----
    const float* xp = x + (size_t)b * DIM * HW + whw + c15;
    float zef[16];
    #pragma unroll
    for (int j = 0; j < 8; ++j) zef[j]     = xp[(size_t)(8 * kg + j) * HW];
    #pragma unroll
    for (int j = 0; j < 8; ++j) zef[8 + j] = xp[(size_t)(32 + 8 * kg + j) * HW];

    bfrag8 zh0, zh1, zl0, zl1;
    #pragma unroll
    for (int j = 0; j < 8; ++j) {
        unsigned short h0 = f32_to_bf16(zef[j]);
        zh0[j] = (short)h0;
        zl0[j] = (short)f32_to_bf16(zef[j] - __uint_as_float((unsigned)h0 << 16));
        unsigned short h1 = f32_to_bf16(zef[8 + j]);
        zh1[j] = (short)h1;
        zl1[j] = (short)f32_to_bf16(zef[8 + j] - __uint_as_float((unsigned)h1 << 16));
    }

    // ---- K loop: 64 tiles of 16 codes ----
    float bs0 = 1e30f, bs1 = 1e30f, bs2 = 1e30f, bs3 = 1e30f;
    int   bk0 = 0, bk1 = 0, bk2 = 0, bk3 = 0;

    #pragma unroll 2
    for (int kt = 0; kt < 64; ++kt) {
        const int kk = kt * 16 + c15;
        const unsigned short* bp = embb + (size_t)kk * DIM + 8 * kg;
        bfrag8 e0 = *reinterpret_cast<const bfrag8*>(bp);        // chans 0..31 slice
        bfrag8 e1 = *reinterpret_cast<const bfrag8*>(bp + 32);   // chans 32..63 slice
        float nv = nrm[kk];

        f32x4 acc = {0.f, 0.f, 0.f, 0.f};
        acc = __builtin_amdgcn_mfma_f32_16x16x32_bf16(zh0, e0, acc, 0, 0, 0);
        acc = __builtin_amdgcn_mfma_f32_16x16x32_bf16(zh1, e1, acc, 0, 0, 0);
        acc = __builtin_amdgcn_mfma_f32_16x16x32_bf16(zl0, e0, acc, 0, 0, 0);
        acc = __builtin_amdgcn_mfma_f32_16x16x32_bf16(zl1, e1, acc, 0, 0, 0);

        float s0 = fmaf(-2.f, acc[0], nv);
        float s1 = fmaf(-2.f, acc[1], nv);
        float s2 = fmaf(-2.f, acc[2], nv);
        float s3 = fmaf(-2.f, acc[3], nv);
        if (s0 < bs0) { bs0 = s0; bk0 = kk; }
        if (s1 < bs1) { bs1 = s1; bk1 = kk; }
        if (s2 < bs2) { bs2 = s2; bk2 = kk; }
        if (s3 < bs3) { bs3 = s3; bk3 = kk; }
    }

    // ---- butterfly argmin across the 16 code-columns (lanes with same kg) ----
    #pragma unroll
    for (int m = 1; m < 16; m <<= 1) {
        float t; int tk;
        t = __shfl_xor(bs0, m, 64); tk = __shfl_xor(bk0, m, 64);
        if (t < bs0 || (t == bs0 && tk < bk0)) { bs0 = t; bk0 = tk; }
        t = __shfl_xor(bs1, m, 64); tk = __shfl_xor(bk1, m, 64);
        if (t < bs1 || (t == bs1 && tk < bk1)) { bs1 = t; bk1 = tk; }
        t = __shfl_xor(bs2, m, 64); tk = __shfl_xor(bk2, m, 64);
        if (t < bs2 || (t == bs2 && tk < bk2)) { bs2 = t; bk2 = tk; }
        t = __shfl_xor(bs3, m, 64); tk = __shfl_xor(bk3, m, 64);
        if (t < bs3 || (t == bs3 && tk < bk3)) { bs3 = t; bk3 = tk; }
    }
    if (c15 == 0) {
        const int pb = wave * 16 + kg * 4;  // D row = kg*4 + reg
        s_idx[pb + 0] = bk0;
        s_idx[pb + 1] = bk1;
        s_idx[pb + 2] = bk2;
        s_idx[pb + 3] = bk3;
    }
    __syncthreads();

    // ---- epilogue: out0 = emb[fk] scattered to (b,c,h,w); loss partial ----
    const int p  = tid & 63;           // pixel within block
    const int cw = tid >> 6;           // chan quarter 0..3
    const int fk = s_idx[p];
    const float4* er = reinterpret_cast<const float4*>(embf + (size_t)fk * DIM + cw * 16);
    float ev[16];
    #pragma unroll
    for (int q = 0; q < 4; ++q) {
        float4 v = er[q];
        ev[4 * q + 0] = v.x; ev[4 * q + 1] = v.y;
        ev[4 * q + 2] = v.z; ev[4 * q + 3] = v.w;
    }
    float*       op = out + (size_t)b * DIM * HW + hw0 + p;
    const float* xq = x   + (size_t)b * DIM * HW + hw0 + p;
    float ls = 0.f;
    #pragma unroll
    for (int i = 0; i < 16; ++i) {
        const size_t c = (size_t)(cw * 16 + i) * HW;
        float e = ev[i];
        op[c] = e;
        float d = xq[c] - e;
        ls = fmaf(d, d, ls);
    }
    #pragma unroll
    for (int m = 32; m > 0; m >>= 1) ls += __shfl_xor(ls, m, 64);
    if (lane == 0) s_part[wave] = ls;
    __syncthreads();
    if (tid == 0)
        partials[blockIdx.x] = s_part[0] + s_part[1] + s_part[2] + s_part[3];
}

// ---------- final deterministic loss reduce ----------
__global__ void vq_loss_final(const float* __restrict__ partials,
                              float* __restrict__ loss_out) {
    __shared__ float sm[4];
    const int tid = threadIdx.x;
    const int lane = tid & 63, wave = tid >> 6;
    float s = 0.f;
    #pragma unroll
    for (int i = 0; i < 4; ++i) s += partials[tid + i * 256];
    #pragma unroll
    for (int m = 32; m > 0; m >>= 1) s += __shfl_xor(s, m, 64);
    if (lane == 0) sm[wave] = s;
    __syncthreads();
    if (tid == 0) {
        double t = (double)sm[0] + sm[1] + sm[2] + sm[3];
        loss_out[0] = (float)(1.25 * t / (double)TOTAL);
    }
}

extern "C" void kernel_launch(void* const* d_in, const int* in_sizes, int n_in,
                              void* d_out, int out_size, void* d_ws, size_t ws_size,
                              hipStream_t stream) {
    const float* x   = (const float*)d_in[0];
    const float* emb = (const float*)d_in[1];
    float* out = (float*)d_out;

    unsigned short* embb = (unsigned short*)d_ws;                 // 128 KiB
    float* nrm      = (float*)((char*)d_ws + K_CAT * DIM * 2);    // 4 KiB
    float* partials = nrm + K_CAT;                                // 4 KiB

    vq_prep<<<K_CAT / 256, 256, 0, stream>>>(emb, embb, nrm);
    vq_argmin<<<NPIX / 64, 256, 0, stream>>>(x, embb, nrm, emb, out, partials);
    vq_loss_final<<<1, 256, 0, stream>>>(partials, out + TOTAL);
}

// Round 3
// 49.285 us; speedup vs baseline: 7.0338x; 1.5625x over previous
//
#include <hip/hip_runtime.h>

#define K_CAT 1024
#define DIM   64
#define HW    4096              // 64*64
#define NPIX  65536             // 16*4096
#define TOTAL 4194304           // NPIX*DIM
#define NBLK  2048              // NPIX/32 pixels-per-block=32

typedef short bfrag8  __attribute__((ext_vector_type(8)));   // 8 bf16
typedef float f32x4   __attribute__((ext_vector_type(4)));
typedef float f32x16  __attribute__((ext_vector_type(16)));

__device__ inline unsigned short f32_to_bf16(float f) {
    unsigned int u = __float_as_uint(f);
    unsigned int r = (u + 0x7fffu + ((u >> 16) & 1u)) >> 16;   // RNE
    return (unsigned short)r;
}

// ---- prep: embb[k][c] = bf16(-2*emb[k][c]) ; nrm[k] = sum_c emb[k][c]^2 ----
__global__ void vq_prep(const float* __restrict__ emb,
                        unsigned short* __restrict__ embb,
                        float* __restrict__ nrm) {
    int k = blockIdx.x * blockDim.x + threadIdx.x;
    if (k >= K_CAT) return;
    const float4* e4 = reinterpret_cast<const float4*>(emb + (size_t)k * DIM);
    unsigned int pk[32];
    float s = 0.f;
    #pragma unroll
    for (int i = 0; i < 16; ++i) {
        float4 v = e4[i];
        s += v.x * v.x + v.y * v.y + v.z * v.z + v.w * v.w;
        pk[2 * i]     = (unsigned)f32_to_bf16(-2.f * v.x) | ((unsigned)f32_to_bf16(-2.f * v.y) << 16);
        pk[2 * i + 1] = (unsigned)f32_to_bf16(-2.f * v.z) | ((unsigned)f32_to_bf16(-2.f * v.w) << 16);
    }
    nrm[k] = s;
    uint4* dst = reinterpret_cast<uint4*>(embb + (size_t)k * DIM);
    #pragma unroll
    for (int i = 0; i < 8; ++i)
        dst[i] = make_uint4(pk[4 * i], pk[4 * i + 1], pk[4 * i + 2], pk[4 * i + 3]);
}

// ---- main: 32 px/block, 4 waves x 256 codes, 32x32x16 MFMA scoring ----
__global__ __launch_bounds__(256) void vq_argmin(
    const float* __restrict__ x, const unsigned short* __restrict__ embb,
    const float* __restrict__ nrm, const float* __restrict__ embf,
    float* __restrict__ out, float* __restrict__ partials)
{
    __shared__ __align__(16) float s_nrm[K_CAT];
    __shared__ float s_sc[4][32];
    __shared__ int   s_id[4][32];
    __shared__ float s_part[4];

    const int tid  = threadIdx.x;
    const int lane = tid & 63;
    const int wave = __builtin_amdgcn_readfirstlane(tid >> 6);
    const int p32  = lane & 31;        // A row=code uses lane&31 too; B col=pixel
    const int h    = lane >> 5;        // k-half select

    const int blk = blockIdx.x;
    const int b   = blk >> 7;          // 128 blocks per image
    const int hw0 = (blk & 127) << 5;  // *32

    // stage nrm into LDS (256 thr x float4 = 1024 floats)
    reinterpret_cast<float4*>(s_nrm)[tid] =
        reinterpret_cast<const float4*>(nrm)[tid];

    // ---- ze B-fragments: pixel = p32, chan k = ks*16 + 8*h + j (held all loop) ----
    const float* xp = x + (size_t)b * DIM * HW + hw0 + p32;
    bfrag8 zb[4];
    #pragma unroll
    for (int ks = 0; ks < 4; ++ks) {
        #pragma unroll
        for (int j = 0; j < 8; ++j) {
            float f = xp[(size_t)(ks * 16 + 8 * h + j) * HW];
            zb[ks][j] = (short)f32_to_bf16(f);
        }
    }

    __syncthreads();   // s_nrm ready

    const int kb = wave * 256;
    float best = 1e30f;
    int   bidx = 0;

    #pragma unroll 2
    for (int t = 0; t < 8; ++t) {
        const int tb = kb + t * 32;
        // A-frags: code row = tb + p32, chans [ks*16 + 8h, +8)
        const unsigned short* ap = embb + (size_t)(tb + p32) * DIM + 8 * h;
        bfrag8 a0 = *reinterpret_cast<const bfrag8*>(ap);
        bfrag8 a1 = *reinterpret_cast<const bfrag8*>(ap + 16);
        bfrag8 a2 = *reinterpret_cast<const bfrag8*>(ap + 32);
        bfrag8 a3 = *reinterpret_cast<const bfrag8*>(ap + 48);

        f32x16 acc = {0.f,0.f,0.f,0.f,0.f,0.f,0.f,0.f,
                      0.f,0.f,0.f,0.f,0.f,0.f,0.f,0.f};
        acc = __builtin_amdgcn_mfma_f32_32x32x16_bf16(a0, zb[0], acc, 0, 0, 0);
        acc = __builtin_amdgcn_mfma_f32_32x32x16_bf16(a1, zb[1], acc, 0, 0, 0);
        acc = __builtin_amdgcn_mfma_f32_32x32x16_bf16(a2, zb[2], acc, 0, 0, 0);
        acc = __builtin_amdgcn_mfma_f32_32x32x16_bf16(a3, zb[3], acc, 0, 0, 0);

        // D: col=lane&31 (pixel), row = (reg&3) + 8*(reg>>2) + 4*h  (code-in-tile)
        #pragma unroll
        for (int r2 = 0; r2 < 4; ++r2) {
            f32x4 nv = *reinterpret_cast<const f32x4*>(s_nrm + tb + 4 * h + 8 * r2);
            #pragma unroll
            for (int q = 0; q < 4; ++q) {
                float sc = acc[r2 * 4 + q] + nv[q];
                int code = tb + 4 * h + 8 * r2 + q;
                if (sc < best) { best = sc; bidx = code; }
            }
        }
    }

    // merge the two half-lanes covering the same pixel
    float ob = __shfl_xor(best, 32, 64);
    int   oi = __shfl_xor(bidx, 32, 64);
    if (ob < best || (ob == best && oi < bidx)) { best = ob; bidx = oi; }
    if (lane < 32) { s_sc[wave][lane] = best; s_id[wave][lane] = bidx; }
    __syncthreads();

    // ---- per-pixel cross-wave merge + gather + write + loss ----
    const int p  = tid & 31;
    const int cw = tid >> 5;           // 8 chan-groups of 8
    float fb = s_sc[0][p]; int fk = s_id[0][p];
    #pragma unroll
    for (int w = 1; w < 4; ++w) {
        float cs = s_sc[w][p]; int ci = s_id[w][p];
        if (cs < fb) { fb = cs; fk = ci; }   // ties -> lower wave (lower code) wins
    }

    const float4* er = reinterpret_cast<const float4*>(embf + (size_t)fk * DIM + cw * 8);
    float4 v0 = er[0], v1 = er[1];
    float ev[8] = {v0.x, v0.y, v0.z, v0.w, v1.x, v1.y, v1.z, v1.w};

    float*       op = out + (size_t)b * DIM * HW + hw0 + p;
    const float* xq = x   + (size_t)b * DIM * HW + hw0 + p;
    float ls = 0.f;
    #pragma unroll
    for (int i = 0; i < 8; ++i) {
        const size_t c = (size_t)(cw * 8 + i) * HW;
        float e = ev[i];
        op[c] = e;
        float d = xq[c] - e;
        ls = fmaf(d, d, ls);
    }
    #pragma unroll
    for (int m = 32; m > 0; m >>= 1) ls += __shfl_xor(ls, m, 64);
    if (lane == 0) s_part[wave] = ls;
    __syncthreads();
    if (tid == 0)
        partials[blk] = s_part[0] + s_part[1] + s_part[2] + s_part[3];
}

// ---- final deterministic loss reduce (2048 partials) ----
__global__ void vq_loss_final(const float* __restrict__ partials,
                              float* __restrict__ loss_out) {
    __shared__ float sm[4];
    const int tid = threadIdx.x;
    const int lane = tid & 63, wave = tid >> 6;
    float s = 0.f;
    #pragma unroll
    for (int i = 0; i < 8; ++i) s += partials[tid + i * 256];
    #pragma unroll
    for (int m = 32; m > 0; m >>= 1) s += __shfl_xor(s, m, 64);
    if (lane == 0) sm[wave] = s;
    __syncthreads();
    if (tid == 0) {
        double t = (double)sm[0] + sm[1] + sm[2] + sm[3];
        loss_out[0] = (float)(1.25 * t / (double)TOTAL);
    }
}

extern "C" void kernel_launch(void* const* d_in, const int* in_sizes, int n_in,
                              void* d_out, int out_size, void* d_ws, size_t ws_size,
                              hipStream_t stream) {
    const float* x   = (const float*)d_in[0];
    const float* emb = (const float*)d_in[1];
    float* out = (float*)d_out;

    unsigned short* embb = (unsigned short*)d_ws;                      // 128 KiB
    float* nrm      = (float*)((char*)d_ws + (size_t)K_CAT * DIM * 2); // 4 KiB
    float* partials = nrm + K_CAT;                                     // 8 KiB

    vq_prep<<<K_CAT / 256, 256, 0, stream>>>(emb, embb, nrm);
    vq_argmin<<<NBLK, 256, 0, stream>>>(x, embb, nrm, emb, out, partials);
    vq_loss_final<<<1, 256, 0, stream>>>(partials, out + TOTAL);
}

// Round 4
// 34.977 us; speedup vs baseline: 9.9110x; 1.4091x over previous
//
#include <hip/hip_runtime.h>

#define K_CAT 1024
#define DIM   64
#define HW    4096              // 64*64
#define NPIX  65536             // 16*4096
#define TOTAL 4194304           // NPIX*DIM
#define NBLK  1024              // NPIX/64: 64 pixels per block

typedef short bfrag8  __attribute__((ext_vector_type(8)));   // 8 bf16
typedef float f32x4   __attribute__((ext_vector_type(4)));
typedef float f32x16  __attribute__((ext_vector_type(16)));

#define KEY_MASK 0xFFFFFC00u    // keep 14 msb of score, low 10 bits = code

__device__ inline unsigned short f32_to_bf16(float f) {
    unsigned int u = __float_as_uint(f);
    unsigned int r = (u + 0x7fffu + ((u >> 16) & 1u)) >> 16;   // RNE
    return (unsigned short)r;
}

// ---- prep: embb[k][c] = bf16(-2*emb[k][c]) ; nrmp[k] = 1 + sum_c emb[k][c]^2 ----
__global__ void vq_prep(const float* __restrict__ emb,
                        unsigned short* __restrict__ embb,
                        float* __restrict__ nrmp) {
    int k = blockIdx.x * blockDim.x + threadIdx.x;
    if (k >= K_CAT) return;
    const float4* e4 = reinterpret_cast<const float4*>(emb + (size_t)k * DIM);
    unsigned int pk[32];
    float s = 0.f;
    #pragma unroll
    for (int i = 0; i < 16; ++i) {
        float4 v = e4[i];
        s += v.x * v.x + v.y * v.y + v.z * v.z + v.w * v.w;
        pk[2 * i]     = (unsigned)f32_to_bf16(-2.f * v.x) | ((unsigned)f32_to_bf16(-2.f * v.y) << 16);
        pk[2 * i + 1] = (unsigned)f32_to_bf16(-2.f * v.z) | ((unsigned)f32_to_bf16(-2.f * v.w) << 16);
    }
    nrmp[k] = 1.0f + s;          // positivity bias: scores in [0.3, 1.7]
    uint4* dst = reinterpret_cast<uint4*>(embb + (size_t)k * DIM);
    #pragma unroll
    for (int i = 0; i < 8; ++i)
        dst[i] = make_uint4(pk[4 * i], pk[4 * i + 1], pk[4 * i + 2], pk[4 * i + 3]);
}

// per-tile packed-key min: key = (score_bits & MASK) | code, depth-4 u32 min tree
__device__ inline unsigned int tile_min_key(const f32x16& acc, int tb, int h) {
    unsigned int k[16];
    #pragma unroll
    for (int r = 0; r < 16; ++r) {
        const int code = tb + (r & 3) + 8 * (r >> 2) + 4 * h;   // D row -> code
        k[r] = (__float_as_uint(acc[r]) & KEY_MASK) | (unsigned int)code;
    }
    #pragma unroll
    for (int s = 8; s > 0; s >>= 1)
        #pragma unroll
        for (int i = 0; i < s; ++i)
            k[i] = k[i] < k[i + s] ? k[i] : k[i + s];
    return k[0];
}

// ---- main: 64 px/block, 4 waves x 256 codes, dual 32x32x16 MFMA chains ----
__global__ __launch_bounds__(256) void vq_argmin(
    const float* __restrict__ x, const unsigned short* __restrict__ embb,
    const float* __restrict__ nrmp, const float* __restrict__ embf,
    float* __restrict__ out, float* __restrict__ partials)
{
    __shared__ __align__(16) float s_nrm[K_CAT];
    __shared__ unsigned int s_key[4][64];
    __shared__ float s_part[4];

    const int tid  = threadIdx.x;
    const int lane = tid & 63;
    const int wave = __builtin_amdgcn_readfirstlane(tid >> 6);
    const int p32  = lane & 31;        // pixel-in-set (B col / D col)
    const int h    = lane >> 5;        // k-half select

    const int blk = blockIdx.x;
    const int b   = blk >> 6;          // 64 blocks per image
    const int hw0 = (blk & 63) << 6;   // *64 pixels

    // stage nrmp into LDS (256 thr x float4 = 1024 floats)
    reinterpret_cast<float4*>(s_nrm)[tid] =
        reinterpret_cast<const float4*>(nrmp)[tid];

    // ---- ze B-fragments for two pixel sets; chan k = ks*16 + 8*h + j ----
    const float* xp0 = x + (size_t)b * DIM * HW + hw0 + p32;
    const float* xp1 = xp0 + 32;
    bfrag8 zb0[4], zb1[4];
    #pragma unroll
    for (int ks = 0; ks < 4; ++ks) {
        #pragma unroll
        for (int j = 0; j < 8; ++j) {
            const size_t coff = (size_t)(ks * 16 + 8 * h + j) * HW;
            zb0[ks][j] = (short)f32_to_bf16(xp0[coff]);
            zb1[ks][j] = (short)f32_to_bf16(xp1[coff]);
        }
    }

    __syncthreads();   // s_nrm ready

    const int kb = wave * 256;
    unsigned int best0 = 0xFFFFFFFFu, best1 = 0xFFFFFFFFu;

    #pragma unroll 2
    for (int t = 0; t < 8; ++t) {
        const int tb = kb + t * 32;
        // A-frags: code row = tb + p32, chans [ks*16 + 8h, +8)
        const unsigned short* ap = embb + (size_t)(tb + p32) * DIM + 8 * h;
        bfrag8 a0 = *reinterpret_cast<const bfrag8*>(ap);
        bfrag8 a1 = *reinterpret_cast<const bfrag8*>(ap + 16);
        bfrag8 a2 = *reinterpret_cast<const bfrag8*>(ap + 32);
        bfrag8 a3 = *reinterpret_cast<const bfrag8*>(ap + 48);

        // C-init = nrmp[code row] (uniform per h-half -> LDS broadcast reads)
        f32x16 acc0;
        #pragma unroll
        for (int q = 0; q < 4; ++q) {
            f32x4 nv = *reinterpret_cast<const f32x4*>(s_nrm + tb + 4 * h + 8 * q);
            acc0[4 * q + 0] = nv[0]; acc0[4 * q + 1] = nv[1];
            acc0[4 * q + 2] = nv[2]; acc0[4 * q + 3] = nv[3];
        }
        f32x16 acc1 = acc0;

        // two independent accumulate chains (pixel sets), interleaved
        acc0 = __builtin_amdgcn_mfma_f32_32x32x16_bf16(a0, zb0[0], acc0, 0, 0, 0);
        acc1 = __builtin_amdgcn_mfma_f32_32x32x16_bf16(a0, zb1[0], acc1, 0, 0, 0);
        acc0 = __builtin_amdgcn_mfma_f32_32x32x16_bf16(a1, zb0[1], acc0, 0, 0, 0);
        acc1 = __builtin_amdgcn_mfma_f32_32x32x16_bf16(a1, zb1[1], acc1, 0, 0, 0);
        acc0 = __builtin_amdgcn_mfma_f32_32x32x16_bf16(a2, zb0[2], acc0, 0, 0, 0);
        acc1 = __builtin_amdgcn_mfma_f32_32x32x16_bf16(a2, zb1[2], acc1, 0, 0, 0);
        acc0 = __builtin_amdgcn_mfma_f32_32x32x16_bf16(a3, zb0[3], acc0, 0, 0, 0);
        acc1 = __builtin_amdgcn_mfma_f32_32x32x16_bf16(a3, zb1[3], acc1, 0, 0, 0);

        const unsigned int m0 = tile_min_key(acc0, tb, h);
        const unsigned int m1 = tile_min_key(acc1, tb, h);
        best0 = best0 < m0 ? best0 : m0;
        best1 = best1 < m1 ? best1 : m1;
    }

    // merge the two k-halves (same pixel, different code rows)
    unsigned int o0 = (unsigned int)__shfl_xor((int)best0, 32, 64);
    unsigned int o1 = (unsigned int)__shfl_xor((int)best1, 32, 64);
    best0 = best0 < o0 ? best0 : o0;
    best1 = best1 < o1 ? best1 : o1;
    if (lane < 32) {
        s_key[wave][p32]      = best0;
        s_key[wave][32 + p32] = best1;
    }
    __syncthreads();

    // ---- per-pixel cross-wave merge + gather + write + loss ----
    const int p  = tid & 63;
    const int cw = tid >> 6;           // 4 chan-groups of 16
    unsigned int k01 = s_key[0][p] < s_key[1][p] ? s_key[0][p] : s_key[1][p];
    unsigned int k23 = s_key[2][p] < s_key[3][p] ? s_key[2][p] : s_key[3][p];
    const int fk = (int)((k01 < k23 ? k01 : k23) & 1023u);

    const float4* er = reinterpret_cast<const float4*>(embf + (size_t)fk * DIM + cw * 16);
    float ev[16];
    #pragma unroll
    for (int q = 0; q < 4; ++q) {
        float4 v = er[q];
        ev[4 * q + 0] = v.x; ev[4 * q + 1] = v.y;
        ev[4 * q + 2] = v.z; ev[4 * q + 3] = v.w;
    }
    float*       op = out + (size_t)b * DIM * HW + hw0 + p;
    const float* xq = x   + (size_t)b * DIM * HW + hw0 + p;
    float ls = 0.f;
    #pragma unroll
    for (int i = 0; i < 16; ++i) {
        const size_t c = (size_t)(cw * 16 + i) * HW;
        float e = ev[i];
        op[c] = e;
        float d = xq[c] - e;
        ls = fmaf(d, d, ls);
    }
    #pragma unroll
    for (int m = 32; m > 0; m >>= 1) ls += __shfl_xor(ls, m, 64);
    if (lane == 0) s_part[wave] = ls;
    __syncthreads();
    if (tid == 0)
        partials[blk] = s_part[0] + s_part[1] + s_part[2] + s_part[3];
}

// ---- final deterministic loss reduce (1024 partials) ----
__global__ void vq_loss_final(const float* __restrict__ partials,
                              float* __restrict__ loss_out) {
    __shared__ float sm[4];
    const int tid = threadIdx.x;
    const int lane = tid & 63, wave = tid >> 6;
    float s = 0.f;
    #pragma unroll
    for (int i = 0; i < 4; ++i) s += partials[tid + i * 256];
    #pragma unroll
    for (int m = 32; m > 0; m >>= 1) s += __shfl_xor(s, m, 64);
    if (lane == 0) sm[wave] = s;
    __syncthreads();
    if (tid == 0) {
        double t = (double)sm[0] + sm[1] + sm[2] + sm[3];
        loss_out[0] = (float)(1.25 * t / (double)TOTAL);
    }
}

extern "C" void kernel_launch(void* const* d_in, const int* in_sizes, int n_in,
                              void* d_out, int out_size, void* d_ws, size_t ws_size,
                              hipStream_t stream) {
    const float* x   = (const float*)d_in[0];
    const float* emb = (const float*)d_in[1];
    float* out = (float*)d_out;

    unsigned short* embb = (unsigned short*)d_ws;                      // 128 KiB
    float* nrmp     = (float*)((char*)d_ws + (size_t)K_CAT * DIM * 2); // 4 KiB
    float* partials = nrmp + K_CAT;                                    // 4 KiB

    vq_prep<<<K_CAT / 256, 256, 0, stream>>>(emb, embb, nrmp);
    vq_argmin<<<NBLK, 256, 0, stream>>>(x, embb, nrmp, emb, out, partials);
    vq_loss_final<<<1, 256, 0, stream>>>(partials, out + TOTAL);
}

// Round 5
// 33.006 us; speedup vs baseline: 10.5028x; 1.0597x over previous
//
#include <hip/hip_runtime.h>

#define K_CAT 1024
#define DIM   64
#define HW    4096              // 64*64
#define NPIX  65536             // 16*4096
#define TOTAL 4194304           // NPIX*DIM
#define NBLK  1024              // 64 pixels per block

typedef short bfrag8 __attribute__((ext_vector_type(8)));   // 8 bf16
typedef int   i32x4  __attribute__((ext_vector_type(4)));
typedef float f32x4  __attribute__((ext_vector_type(4)));
typedef float f32x16 __attribute__((ext_vector_type(16)));

#define KEY_MASK 0xFFFFFC00u    // keep 22 msb of score, low 10 bits = code

__device__ inline unsigned int f32_to_bf16(float f) {
    unsigned int u = __float_as_uint(f);
    return (u + 0x7fffu + ((u >> 16) & 1u)) >> 16;   // RNE
}
__device__ inline unsigned int umin2(unsigned int a, unsigned int b) { return a < b ? a : b; }
__device__ inline unsigned int umin3(unsigned int a, unsigned int b, unsigned int c) {
    return umin2(umin2(a, b), c);   // clang fuses to v_min3_u32
}

// ---- prep: embb[k][c] = bf16(-2*emb[k][c]) ; nrmp[k] = 1 + sum_c emb[k][c]^2 ----
__global__ void vq_prep(const float* __restrict__ emb,
                        unsigned short* __restrict__ embb,
                        float* __restrict__ nrmp) {
    int k = blockIdx.x * blockDim.x + threadIdx.x;
    if (k >= K_CAT) return;
    const float4* e4 = reinterpret_cast<const float4*>(emb + (size_t)k * DIM);
    unsigned int pk[32];
    float s = 0.f;
    #pragma unroll
    for (int i = 0; i < 16; ++i) {
        float4 v = e4[i];
        s += v.x * v.x + v.y * v.y + v.z * v.z + v.w * v.w;
        pk[2 * i]     = f32_to_bf16(-2.f * v.x) | (f32_to_bf16(-2.f * v.y) << 16);
        pk[2 * i + 1] = f32_to_bf16(-2.f * v.z) | (f32_to_bf16(-2.f * v.w) << 16);
    }
    nrmp[k] = 1.0f + s;          // positivity bias: scores in [0.3, 1.7]
    uint4* dst = reinterpret_cast<uint4*>(embb + (size_t)k * DIM);
    #pragma unroll
    for (int i = 0; i < 8; ++i)
        dst[i] = make_uint4(pk[4 * i], pk[4 * i + 1], pk[4 * i + 2], pk[4 * i + 3]);
}

// per-tile packed-key min via min3 tree
__device__ inline unsigned int tile_min_key(const f32x16& acc, int tb, int h) {
    unsigned int k[16];
    #pragma unroll
    for (int r = 0; r < 16; ++r) {
        const int code = tb + (r & 3) + 8 * (r >> 2) + 4 * h;   // D row -> code
        k[r] = (__float_as_uint(acc[r]) & KEY_MASK) | (unsigned int)code;
    }
    unsigned int m0 = umin3(k[0], k[1], k[2]);
    unsigned int m1 = umin3(k[3], k[4], k[5]);
    unsigned int m2 = umin3(k[6], k[7], k[8]);
    unsigned int m3 = umin3(k[9], k[10], k[11]);
    unsigned int m4 = umin3(k[12], k[13], k[14]);
    return umin2(umin3(m0, m1, k[15]), umin3(m2, m3, m4));
}

// ---- main: 64 px/block staged in LDS, 4 waves x 256 codes, dual MFMA chains ----
__global__ __launch_bounds__(256, 4) void vq_argmin(
    const float* __restrict__ x, const unsigned short* __restrict__ embb,
    const float* __restrict__ nrmp, const float* __restrict__ embf,
    float* __restrict__ out, float* __restrict__ partials)
{
    __shared__ unsigned int s_pair[32 * 64];        // 8 KB  bf16 chan-pairs [c2][px]
    __shared__ float        s_xf[64 * 64];          // 16 KB f32 x-tile [c][px]
    __shared__ __align__(16) float s_nrm[K_CAT];    // 4 KB
    __shared__ unsigned int s_key[4][64];
    __shared__ float        s_part[4];

    const int tid  = threadIdx.x;
    const int lane = tid & 63;
    const int wave = __builtin_amdgcn_readfirstlane(tid >> 6);
    const int p32  = lane & 31;        // pixel-in-set (B col / D col)
    const int h    = lane >> 5;        // k-half select

    const int blk = blockIdx.x;
    const int b   = blk >> 6;          // 64 blocks per image
    const int hw0 = (blk & 63) << 6;   // *64 pixels

    // ---- stage nrmp (4 KB) ----
    reinterpret_cast<float4*>(s_nrm)[tid] =
        reinterpret_cast<const float4*>(nrmp)[tid];

    // ---- stage x-tile: thread handles chans (2*c2w, 2*c2w+1) x px0..px0+7 ----
    {
        const int c2w = tid >> 3;              // 0..31
        const int px0 = (tid & 7) * 8;         // 0..56
        const float* r0 = x + (size_t)b * DIM * HW + (size_t)(2 * c2w) * HW + hw0 + px0;
        const float* r1 = r0 + HW;
        float4 a0 = reinterpret_cast<const float4*>(r0)[0];
        float4 a1 = reinterpret_cast<const float4*>(r0)[1];
        float4 b0 = reinterpret_cast<const float4*>(r1)[0];
        float4 b1 = reinterpret_cast<const float4*>(r1)[1];
        // f32 copy for epilogue
        float4* f0 = reinterpret_cast<float4*>(&s_xf[(2 * c2w) * 64 + px0]);
        f0[0] = a0; f0[1] = a1;
        float4* f1 = reinterpret_cast<float4*>(&s_xf[(2 * c2w + 1) * 64 + px0]);
        f1[0] = b0; f1[1] = b1;
        // bf16 pair table: pair(px) = [bf16(even ch) | bf16(odd ch)<<16]
        float ea[8] = {a0.x, a0.y, a0.z, a0.w, a1.x, a1.y, a1.z, a1.w};
        float eb[8] = {b0.x, b0.y, b0.z, b0.w, b1.x, b1.y, b1.z, b1.w};
        unsigned int pr[8];
        #pragma unroll
        for (int i = 0; i < 8; ++i)
            pr[i] = f32_to_bf16(ea[i]) | (f32_to_bf16(eb[i]) << 16);
        uint4* pp = reinterpret_cast<uint4*>(&s_pair[c2w * 64 + px0]);
        pp[0] = make_uint4(pr[0], pr[1], pr[2], pr[3]);
        pp[1] = make_uint4(pr[4], pr[5], pr[6], pr[7]);
    }
    __syncthreads();

    // ---- B-fragments from LDS: chan pair c2 = ks*8 + 4h + m, px = p32 (+32) ----
    bfrag8 zb0[4], zb1[4];
    {
        const unsigned int* pb = s_pair + h * 256 + p32;   // fold 4h*64 into base
        #pragma unroll
        for (int ks = 0; ks < 4; ++ks) {
            i32x4 t0, t1;
            #pragma unroll
            for (int m = 0; m < 4; ++m) {
                t0[m] = (int)pb[(ks * 8 + m) * 64];        // imm offsets
                t1[m] = (int)pb[(ks * 8 + m) * 64 + 32];
            }
            zb0[ks] = __builtin_bit_cast(bfrag8, t0);
            zb1[ks] = __builtin_bit_cast(bfrag8, t1);
        }
    }

    const int kb = wave * 256;
    unsigned int best0 = 0xFFFFFFFFu, best1 = 0xFFFFFFFFu;

    #pragma unroll 2
    for (int t = 0; t < 8; ++t) {
        const int tb = kb + t * 32;
        const unsigned short* ap = embb + (size_t)(tb + p32) * DIM + 8 * h;
        bfrag8 a0 = *reinterpret_cast<const bfrag8*>(ap);
        bfrag8 a1 = *reinterpret_cast<const bfrag8*>(ap + 16);
        bfrag8 a2 = *reinterpret_cast<const bfrag8*>(ap + 32);
        bfrag8 a3 = *reinterpret_cast<const bfrag8*>(ap + 48);

        // C-init = nrmp[code row]
        f32x16 acc0;
        #pragma unroll
        for (int q = 0; q < 4; ++q) {
            f32x4 nv = *reinterpret_cast<const f32x4*>(s_nrm + tb + 4 * h + 8 * q);
            acc0[4 * q + 0] = nv[0]; acc0[4 * q + 1] = nv[1];
            acc0[4 * q + 2] = nv[2]; acc0[4 * q + 3] = nv[3];
        }
        f32x16 acc1 = acc0;

        acc0 = __builtin_amdgcn_mfma_f32_32x32x16_bf16(a0, zb0[0], acc0, 0, 0, 0);
        acc1 = __builtin_amdgcn_mfma_f32_32x32x16_bf16(a0, zb1[0], acc1, 0, 0, 0);
        acc0 = __builtin_amdgcn_mfma_f32_32x32x16_bf16(a1, zb0[1], acc0, 0, 0, 0);
        acc1 = __builtin_amdgcn_mfma_f32_32x32x16_bf16(a1, zb1[1], acc1, 0, 0, 0);
        acc0 = __builtin_amdgcn_mfma_f32_32x32x16_bf16(a2, zb0[2], acc0, 0, 0, 0);
        acc1 = __builtin_amdgcn_mfma_f32_32x32x16_bf16(a2, zb1[2], acc1, 0, 0, 0);
        acc0 = __builtin_amdgcn_mfma_f32_32x32x16_bf16(a3, zb0[3], acc0, 0, 0, 0);
        acc1 = __builtin_amdgcn_mfma_f32_32x32x16_bf16(a3, zb1[3], acc1, 0, 0, 0);

        best0 = umin2(best0, tile_min_key(acc0, tb, h));
        best1 = umin2(best1, tile_min_key(acc1, tb, h));
    }

    // merge the two k-halves (same pixel, different code rows)
    best0 = umin2(best0, (unsigned int)__shfl_xor((int)best0, 32, 64));
    best1 = umin2(best1, (unsigned int)__shfl_xor((int)best1, 32, 64));
    if (lane < 32) {
        s_key[wave][p32]      = best0;
        s_key[wave][32 + p32] = best1;
    }
    __syncthreads();

    // ---- per-pixel cross-wave merge + gather + write + loss ----
    const int p  = tid & 63;
    const int cw = tid >> 6;           // 4 chan-groups of 16
    unsigned int k01 = umin2(s_key[0][p], s_key[1][p]);
    unsigned int k23 = umin2(s_key[2][p], s_key[3][p]);
    const int fk = (int)(umin2(k01, k23) & 1023u);

    const float4* er = reinterpret_cast<const float4*>(embf + (size_t)fk * DIM + cw * 16);
    float ev[16];
    #pragma unroll
    for (int q = 0; q < 4; ++q) {
        float4 v = er[q];
        ev[4 * q + 0] = v.x; ev[4 * q + 1] = v.y;
        ev[4 * q + 2] = v.z; ev[4 * q + 3] = v.w;
    }
    float*       op = out  + (size_t)b * DIM * HW + hw0 + p;
    const float* xr = s_xf + (cw * 16) * 64 + p;
    float ls = 0.f;
    #pragma unroll
    for (int i = 0; i < 16; ++i) {
        float e = ev[i];
        op[(size_t)(cw * 16 + i) * HW] = e;
        float d = xr[i * 64] - e;                 // LDS imm-offset reads
        ls = fmaf(d, d, ls);
    }
    #pragma unroll
    for (int m = 32; m > 0; m >>= 1) ls += __shfl_xor(ls, m, 64);
    if (lane == 0) s_part[wave] = ls;
    __syncthreads();
    if (tid == 0)
        partials[blk] = s_part[0] + s_part[1] + s_part[2] + s_part[3];
}

// ---- final deterministic loss reduce (1024 partials) ----
__global__ void vq_loss_final(const float* __restrict__ partials,
                              float* __restrict__ loss_out) {
    __shared__ float sm[4];
    const int tid = threadIdx.x;
    const int lane = tid & 63, wave = tid >> 6;
    float s = 0.f;
    #pragma unroll
    for (int i = 0; i < 4; ++i) s += partials[tid + i * 256];
    #pragma unroll
    for (int m = 32; m > 0; m >>= 1) s += __shfl_xor(s, m, 64);
    if (lane == 0) sm[wave] = s;
    __syncthreads();
    if (tid == 0) {
        double t = (double)sm[0] + sm[1] + sm[2] + sm[3];
        loss_out[0] = (float)(1.25 * t / (double)TOTAL);
    }
}

extern "C" void kernel_launch(void* const* d_in, const int* in_sizes, int n_in,
                              void* d_out, int out_size, void* d_ws, size_t ws_size,
                              hipStream_t stream) {
    const float* x   = (const float*)d_in[0];
    const float* emb = (const float*)d_in[1];
    float* out = (float*)d_out;

    unsigned short* embb = (unsigned short*)d_ws;                      // 128 KiB
    float* nrmp     = (float*)((char*)d_ws + (size_t)K_CAT * DIM * 2); // 4 KiB
    float* partials = nrmp + K_CAT;                                    // 4 KiB

    vq_prep<<<K_CAT / 256, 256, 0, stream>>>(emb, embb, nrmp);
    vq_argmin<<<NBLK, 256, 0, stream>>>(x, embb, nrmp, emb, out, partials);
    vq_loss_final<<<1, 256, 0, stream>>>(partials, out + TOTAL);
}